// Round 5
// baseline (1333.866 us; speedup 1.0000x reference)
//
#include <hip/hip_runtime.h>
#include <math.h>

#define B_  64
#define N_  1024
#define H_  64
#define IN_ 512
#define G4  256   // 4*H

// ---------------------------------------------------------------------------
// Kernel A: xg[b][n][g] = sum_k x[b][n][k] * W_ih[g][k] + b_ih[g] + b_hh[g]
// 128x128 tile, BK=32, 256 threads, 8x8 microtile. (unchanged this round)
// ---------------------------------------------------------------------------
__global__ __launch_bounds__(256) void gemm_xg_kernel(
    const float* __restrict__ x,     // [64][1024][512]
    const float* __restrict__ Wih,   // [256][512]
    const float* __restrict__ bih,
    const float* __restrict__ bhh,
    float* __restrict__ xg)          // [64][1024][256]
{
    __shared__ float As[32][132];    // [k][m_local], +4 pad
    __shared__ float Bs[32][132];    // [k][g_local]

    const int tid = threadIdx.x;
    const int g0  = blockIdx.x * 128;
    const int m0  = blockIdx.y * 128;

    const int tx = tid & 15;
    const int ty = tid >> 4;

    const int r8 = tid >> 3;
    const int kq = tid & 7;

    float acc[8][8];
    #pragma unroll
    for (int i = 0; i < 8; ++i)
        #pragma unroll
        for (int j = 0; j < 8; ++j) acc[i][j] = 0.f;

    for (int k0 = 0; k0 < IN_; k0 += 32) {
        #pragma unroll
        for (int it = 0; it < 4; ++it) {
            const int row = r8 + 32 * it;
            const int m   = m0 + row;
            const int bb  = m & 63;
            const int nn  = m >> 6;
            const float4 v = *(const float4*)&x[((size_t)bb * N_ + nn) * IN_ + k0 + kq * 4];
            As[kq * 4 + 0][row] = v.x;
            As[kq * 4 + 1][row] = v.y;
            As[kq * 4 + 2][row] = v.z;
            As[kq * 4 + 3][row] = v.w;
        }
        #pragma unroll
        for (int it = 0; it < 4; ++it) {
            const int row = r8 + 32 * it;
            const float4 v = *(const float4*)&Wih[(size_t)(g0 + row) * IN_ + k0 + kq * 4];
            Bs[kq * 4 + 0][row] = v.x;
            Bs[kq * 4 + 1][row] = v.y;
            Bs[kq * 4 + 2][row] = v.z;
            Bs[kq * 4 + 3][row] = v.w;
        }
        __syncthreads();

        #pragma unroll
        for (int k = 0; k < 32; ++k) {
            const float4 a0 = *(const float4*)&As[k][ty * 4];
            const float4 a1 = *(const float4*)&As[k][64 + ty * 4];
            const float4 b0 = *(const float4*)&Bs[k][tx * 4];
            const float4 b1 = *(const float4*)&Bs[k][64 + tx * 4];
            const float ar[8] = {a0.x, a0.y, a0.z, a0.w, a1.x, a1.y, a1.z, a1.w};
            const float br[8] = {b0.x, b0.y, b0.z, b0.w, b1.x, b1.y, b1.z, b1.w};
            #pragma unroll
            for (int i = 0; i < 8; ++i)
                #pragma unroll
                for (int j = 0; j < 8; ++j)
                    acc[i][j] = fmaf(ar[i], br[j], acc[i][j]);
        }
        __syncthreads();
    }

    float bias[8];
    #pragma unroll
    for (int j = 0; j < 4; ++j) {
        bias[j]     = bih[g0 + tx * 4 + j]      + bhh[g0 + tx * 4 + j];
        bias[4 + j] = bih[g0 + 64 + tx * 4 + j] + bhh[g0 + 64 + tx * 4 + j];
    }

    #pragma unroll
    for (int i = 0; i < 8; ++i) {
        const int row = (i < 4) ? (ty * 4 + i) : (64 + ty * 4 + i - 4);
        const int m   = m0 + row;
        const size_t base = ((size_t)(m & 63) * N_ + (m >> 6)) * G4;
        float4 o0, o1;
        o0.x = acc[i][0] + bias[0]; o0.y = acc[i][1] + bias[1];
        o0.z = acc[i][2] + bias[2]; o0.w = acc[i][3] + bias[3];
        o1.x = acc[i][4] + bias[4]; o1.y = acc[i][5] + bias[5];
        o1.z = acc[i][6] + bias[6]; o1.w = acc[i][7] + bias[7];
        *(float4*)&xg[base + g0 + tx * 4]      = o0;
        *(float4*)&xg[base + g0 + 64 + tx * 4] = o1;
    }
}

// ---------------------------------------------------------------------------
// Kernel B v5: ONE WAVE per batch row — zero barriers, zero cross-wave sync.
// Lane l owns all four gates of h-element l (W_hh rows l, 64+l, 128+l, 192+l
// live in 256 VGPRs). Per step:
//   - 4 coalesced dword loads of xg (distance-2 register prefetch, no LDS)
//   - h broadcast: 1 ds_write_b32 + 16 broadcast ds_read_b128 (no barrier:
//     single wave is lockstep, compiler inserts the lgkmcnt wait)
//   - 4 dot products of length 64 as float2 chains (v_pk_fma eligible)
//   - activations + c/h update fully in-lane, zero divergence
//   - out store is fire-and-forget (nothing ever drains vmcnt)
// ---------------------------------------------------------------------------
__device__ __forceinline__ float sig_(float x) {
    return __builtin_amdgcn_rcpf(1.f + __expf(-x));
}
__device__ __forceinline__ float tanh_(float x) {
    return 1.f - 2.f * __builtin_amdgcn_rcpf(1.f + __expf(2.f * x));
}

__global__ __launch_bounds__(64, 1) void lstm_scan_kernel(
    const float* __restrict__ xg,    // [B][N][256]
    const float* __restrict__ Whh,   // [256][64]
    float* __restrict__ out)         // [B][N][64]
{
    const int l  = threadIdx.x;      // 0..63
    const int bb = blockIdx.x;

    __shared__ float h_sh[64];

    // W_hh rows {l, 64+l, 128+l, 192+l} -> 128 float2 = 256 VGPRs
    float2 W[4][32];
    #pragma unroll
    for (int q = 0; q < 4; ++q)
        #pragma unroll
        for (int k = 0; k < 32; ++k)
            W[q][k] = *(const float2*)&Whh[(size_t)(q * 64 + l) * H_ + k * 2];

    const float* xg_b = xg + (size_t)bb * N_ * G4;

    // distance-2 prefetch buffers: pre[p] holds xg gates for step n (p = n&1)
    float pre[2][4];
    #pragma unroll
    for (int q = 0; q < 4; ++q) pre[0][q] = xg_b[0 * G4 + q * 64 + l];
    #pragma unroll
    for (int q = 0; q < 4; ++q) pre[1][q] = xg_b[1 * G4 + q * 64 + l];

    h_sh[l] = 0.f;      // single wave: no barrier needed anywhere
    float c = 0.f;

    for (int n = 0; n < N_; n += 2) {
        #pragma unroll
        for (int p = 0; p < 2; ++p) {
            const int nn = n + p;

            // consume pre[p] into the 4 accumulator chains (float2 halves)
            float2 A0 = {pre[p][0], 0.f};
            float2 A1 = {pre[p][1], 0.f};
            float2 A2 = {pre[p][2], 0.f};
            float2 A3 = {pre[p][3], 0.f};

            // issue prefetch for step nn+2 (consumed two iterations later)
            if (nn + 2 < N_) {
                const float* src = xg_b + (size_t)(nn + 2) * G4 + l;
                pre[p][0] = src[0];
                pre[p][1] = src[64];
                pre[p][2] = src[128];
                pre[p][3] = src[192];
            }

            // 4 x dot(W_row, h): 16 broadcast b128 reads, 256 FMAs (pk pairs)
            #pragma unroll
            for (int kk = 0; kk < 16; ++kk) {
                const float4 hv = *(const float4*)&h_sh[kk * 4];
                const float2 hA = {hv.x, hv.y};
                const float2 hB = {hv.z, hv.w};
                const float2 w0a = W[0][2 * kk],     w0b = W[0][2 * kk + 1];
                const float2 w1a = W[1][2 * kk],     w1b = W[1][2 * kk + 1];
                const float2 w2a = W[2][2 * kk],     w2b = W[2][2 * kk + 1];
                const float2 w3a = W[3][2 * kk],     w3b = W[3][2 * kk + 1];
                A0.x = fmaf(w0a.x, hA.x, A0.x); A0.y = fmaf(w0a.y, hA.y, A0.y);
                A1.x = fmaf(w1a.x, hA.x, A1.x); A1.y = fmaf(w1a.y, hA.y, A1.y);
                A2.x = fmaf(w2a.x, hA.x, A2.x); A2.y = fmaf(w2a.y, hA.y, A2.y);
                A3.x = fmaf(w3a.x, hA.x, A3.x); A3.y = fmaf(w3a.y, hA.y, A3.y);
                A0.x = fmaf(w0b.x, hB.x, A0.x); A0.y = fmaf(w0b.y, hB.y, A0.y);
                A1.x = fmaf(w1b.x, hB.x, A1.x); A1.y = fmaf(w1b.y, hB.y, A1.y);
                A2.x = fmaf(w2b.x, hB.x, A2.x); A2.y = fmaf(w2b.y, hB.y, A2.y);
                A3.x = fmaf(w3b.x, hB.x, A3.x); A3.y = fmaf(w3b.y, hB.y, A3.y);
            }

            // activations + cell update, fully in-lane (zero divergence)
            const float gi = sig_(A0.x + A0.y);
            const float gf = sig_(A1.x + A1.y);
            const float gg = tanh_(A2.x + A2.y);
            const float go = sig_(A3.x + A3.y);
            c = fmaf(gf, c, gi * gg);
            const float h = go * tanh_(c);

            h_sh[l] = h;                                   // next step's input
            out[((size_t)bb * N_ + nn) * H_ + l] = h;      // fire-and-forget
        }
    }
}

extern "C" void kernel_launch(void* const* d_in, const int* in_sizes, int n_in,
                              void* d_out, int out_size, void* d_ws, size_t ws_size,
                              hipStream_t stream)
{
    const float* x   = (const float*)d_in[0];
    const float* Wih = (const float*)d_in[1];
    const float* Whh = (const float*)d_in[2];
    const float* bih = (const float*)d_in[3];
    const float* bhh = (const float*)d_in[4];
    float* out = (float*)d_out;
    float* xg  = (float*)d_ws;   // 64 MiB scratch, layout [B][N][256]

    dim3 ggrid(2, 512);
    gemm_xg_kernel<<<ggrid, 256, 0, stream>>>(x, Wih, bih, bhh, xg);
    lstm_scan_kernel<<<B_, 64, 0, stream>>>(xg, Whh, out);
}